// Round 7
// baseline (1505.880 us; speedup 1.0000x reference)
//
#include <hip/hip_runtime.h>
#include <hip/hip_cooperative_groups.h>
#include <math.h>

namespace cg = cooperative_groups;

#define NT 256
#define NTC 512
typedef _Float16 f16;
typedef _Float16 half8 __attribute__((ext_vector_type(8)));
typedef _Float16 half4 __attribute__((ext_vector_type(4)));
typedef float floatx4 __attribute__((ext_vector_type(4)));

// DPP row_shr sum (VALU-only reduce within 16-lane rows; full sum valid at l15==0 — HW-verified r3)
#define ROWSHR_ADD(v, N) \
  (v) += __int_as_float(__builtin_amdgcn_update_dpp(0, __float_as_int(v), 0x110 | (N), 0xF, 0xF, true))

// ---------------- workspace layout (bytes) ----------------
#define WD1_OFF  0              // 896*800*2 = 1433600
#define WD2_OFF  1433600
#define WOT_OFF  2867200        // 784*16*4 = 50176
#define D8_OFF   2917376        // 196*4 = 784 (pad to 2918400)
#define HBUF_OFF 2918400        // 32768*800*2 = 52428800 -> end 55347200
#define D1_OFF   55347200       // 52428800 -> end 107776000
#define WPKH_OFF 55347200       // 9*208*224*2 = 838656
#define WPKL_OFF 56185856       // 838656 -> end 57024512 (inside d1 region)
#define SSE      38464          // scratch slot stride in floats (>=196*196)
// scratch slots (floats @ hbuf base, dead before k_caps writes hbuf):
// 0:G  1..8:Q_1..Q_8 (Q_i = W3^i; K_i = Q_i^T)  9..15:T_1..7  16..22:H_1..7
// 23: misc — gtab[0..1567] z[1600..1795] dtab[1800..3367] gbuf[3400..4967]

__device__ inline void glds16(const void* g, void* l) {
  __builtin_amdgcn_global_load_lds((const __attribute__((address_space(1))) void*)g,
                                   (__attribute__((address_space(3))) void*)l, 16, 0, 0);
}

// ---------------- prep: decoder weights ----------------
__global__ void k_prep_wd(const float* __restrict__ Wd, f16* __restrict__ W16) {
  int idx = blockIdx.x * NT + threadIdx.x;
  if (idx >= 896 * 800) return;
  int n = idx / 800, k = idx - n * 800;
  W16[idx] = (f16)((n < 784 && k < 784) ? Wd[n * 784 + k] : 0.f);
}

__global__ void k_prep_wo(const float* __restrict__ Wo, float* __restrict__ WoT) {
  int idx = blockIdx.x * NT + threadIdx.x;
  if (idx >= 784 * 16) return;
  int f = idx >> 4, n = idx & 15;
  WoT[idx] = (n < 10) ? Wo[n * 784 + f] : 0.f;
}

// ---------------- prep: ONE cooperative kernel, 6 grid-synced stages ----------------
// 196x196 fp32 matmul unit: 64 outputs x 4 K-slices (49) per 256-thread block.
__device__ inline void mm_unit(const float* __restrict__ A, const float* __restrict__ B,
                               float* __restrict__ C, int ta, int u, float* red, int tid) {
  __syncthreads();
  int o = u * 64 + (tid & 63);
  int ks = tid >> 6;
  float s = 0.f;
  int p = 0, r = 0;
  if (o < 38416) {
    p = o / 196; r = o - p * 196;
    const int c0 = ks * 49;
    #pragma unroll 7
    for (int c = c0; c < c0 + 49; ++c) {
      float a = ta ? A[c * 196 + p] : A[p * 196 + c];
      s += a * B[c * 196 + r];
    }
  }
  red[tid] = s;
  __syncthreads();
  if (tid < 64 && o < 38416)
    C[p * 196 + r] = red[tid] + red[tid + 64] + red[tid + 128] + red[tid + 192];
}

#define SL(i) (scr + (size_t)(i) * SSE)
#define PU 601   // mm units per 196x196 product

__global__ __launch_bounds__(NT, 4)
void k_prep_all(const float* __restrict__ W1, const float* __restrict__ W2,
                const float* __restrict__ W3, const float* __restrict__ b1,
                const float* __restrict__ b3,
                float* __restrict__ scr, float* __restrict__ d8out,
                f16* __restrict__ Wph, f16* __restrict__ Wpl) {
  __shared__ float red[256];
  __shared__ float sc[196], sd[196], st[196];
  const int tid = threadIdx.x;
  cg::grid_group grid = cg::this_grid();

  float* G    = scr;
  float* gtab = scr + (size_t)23 * SSE;
  float* zg   = gtab + 1600;
  float* dtab = gtab + 1800;
  float* gbuf = gtab + 3400;

  // ---- Stage A: G = W1^T W2 ; Q2 = W3 W3 ; Q1 = copy(W3) ; z + c-chain/d_i/d8 ----
  for (int t = blockIdx.x; t < 2 * PU + 152; t += gridDim.x) {
    if (t < PU) {
      mm_unit(W1, W2, G, 1, t, red, tid);
    } else if (t < 2 * PU) {
      mm_unit(W3, W3, SL(2), 0, t - PU, red, tid);
    } else if (t < 2 * PU + 151) {
      int idx = (t - 2 * PU) * NT + tid;
      if (idx < 38416) SL(1)[idx] = W3[idx];
    } else {
      // z = W2^T b1
      for (int q = tid; q < 196; q += NT) {
        float s = 0.f;
        for (int f = 0; f < 196; ++f) s += b1[f] * W2[f * 196 + q];
        zg[q] = s;
      }
      // c-chain: c_0=b3, c_{j+1}=W3 c_j ; dtab[i]=sum_{j<i} c_j ; d8=dtab[7]+c_7
      for (int q = tid; q < 196; q += NT) { sc[q] = b3[q]; sd[q] = 0.f; dtab[q] = 0.f; }
      __syncthreads();
      for (int j = 0; j < 7; ++j) {
        for (int q = tid; q < 196; q += NT) {
          float s = 0.f;
          for (int c = 0; c < 196; ++c) s += W3[q * 196 + c] * sc[c];
          st[q] = s;
          sd[q] += sc[q];
          dtab[(j + 1) * 196 + q] = sd[q];
        }
        __syncthreads();
        for (int q = tid; q < 196; q += NT) sc[q] = st[q];
        __syncthreads();
      }
      for (int q = tid; q < 196; q += NT) d8out[q] = sd[q] + sc[q];
    }
  }
  grid.sync();

  // ---- Stage B: Q3=Q2 W3 ; Q4=Q2 Q2 ; T1=W3^T G ; T2=Q2^T G ; g_i = z + G^T d_i ----
  for (int t = blockIdx.x; t < 4 * PU + 8; t += gridDim.x) {
    if (t < PU)          mm_unit(SL(2), W3,    SL(3),  0, t,          red, tid);
    else if (t < 2 * PU) mm_unit(SL(2), SL(2), SL(4),  0, t - PU,     red, tid);
    else if (t < 3 * PU) mm_unit(W3,    G,     SL(9),  1, t - 2 * PU, red, tid);
    else if (t < 4 * PU) mm_unit(SL(2), G,     SL(10), 1, t - 3 * PU, red, tid);
    else {
      int i = t - 4 * PU;
      for (int q = tid; q < 196; q += NT) {
        float s = zg[q];
        for (int k = 0; k < 196; ++k) s += G[k * 196 + q] * dtab[i * 196 + k];
        gbuf[i * 196 + q] = s;
      }
    }
  }
  grid.sync();

  // ---- Stage C: Q5..Q8 = Q4 {Q1..Q4} ; T3,T4 ; H1,H2 ; ghat_0..2 ----
  for (int t = blockIdx.x; t < 8 * PU + 3; t += gridDim.x) {
    if (t < PU)          mm_unit(SL(4),  W3,    SL(5),  0, t,          red, tid);
    else if (t < 2 * PU) mm_unit(SL(4),  SL(2), SL(6),  0, t - PU,     red, tid);
    else if (t < 3 * PU) mm_unit(SL(4),  SL(3), SL(7),  0, t - 2 * PU, red, tid);
    else if (t < 4 * PU) mm_unit(SL(4),  SL(4), SL(8),  0, t - 3 * PU, red, tid);
    else if (t < 5 * PU) mm_unit(SL(3),  G,     SL(11), 1, t - 4 * PU, red, tid);
    else if (t < 6 * PU) mm_unit(SL(4),  G,     SL(12), 1, t - 5 * PU, red, tid);
    else if (t < 7 * PU) mm_unit(SL(9),  W3,    SL(16), 0, t - 6 * PU, red, tid);
    else if (t < 8 * PU) mm_unit(SL(10), SL(2), SL(17), 0, t - 7 * PU, red, tid);
    else {
      int i = t - 8 * PU;   // 0..2
      for (int q = tid; q < 196; q += NT) {
        float s;
        if (i == 0) s = gbuf[q];
        else {
          const float* Qi = SL(i);
          s = 0.f;
          for (int n = 0; n < 196; ++n) s += Qi[n * 196 + q] * gbuf[i * 196 + n];
        }
        gtab[i * 196 + q] = s;
      }
    }
  }
  grid.sync();

  // ---- Stage D: T5,T6,T7 ; H3,H4 ; ghat_3..7 ----
  for (int t = blockIdx.x; t < 5 * PU + 5; t += gridDim.x) {
    if (t < PU)          mm_unit(SL(5),  G,     SL(13), 1, t,          red, tid);
    else if (t < 2 * PU) mm_unit(SL(6),  G,     SL(14), 1, t - PU,     red, tid);
    else if (t < 3 * PU) mm_unit(SL(7),  G,     SL(15), 1, t - 2 * PU, red, tid);
    else if (t < 4 * PU) mm_unit(SL(11), SL(3), SL(18), 0, t - 3 * PU, red, tid);
    else if (t < 5 * PU) mm_unit(SL(12), SL(4), SL(19), 0, t - 4 * PU, red, tid);
    else {
      int i = t - 5 * PU + 3;   // 3..7
      const float* Qi = SL(i);
      for (int q = tid; q < 196; q += NT) {
        float s = 0.f;
        for (int n = 0; n < 196; ++n) s += Qi[n * 196 + q] * gbuf[i * 196 + n];
        gtab[i * 196 + q] = s;
      }
    }
  }
  grid.sync();

  // ---- Stage E: H5,H6,H7 ----
  for (int t = blockIdx.x; t < 3 * PU; t += gridDim.x) {
    if (t < PU)          mm_unit(SL(13), SL(5), SL(20), 0, t,          red, tid);
    else if (t < 2 * PU) mm_unit(SL(14), SL(6), SL(21), 0, t - PU,     red, tid);
    else                 mm_unit(SL(15), SL(7), SL(22), 0, t - 2 * PU, red, tid);
  }
  grid.sync();

  // ---- Stage F: pack Wpk[9][208][224] f16 hi/lo ----
  for (int t = blockIdx.x; t < 1638; t += gridDim.x) {
    int idx = t * NT + tid;
    if (idx < 9 * 208 * 224) {
      int s = idx / (208 * 224), rem = idx - s * (208 * 224);
      int n = rem / 224, k = rem - n * 224;
      float v = 0.f;
      if (k < 196) {
        if (n < 196) {
          if (s == 8) v = SL(8)[n * 196 + k];                    // K8 = Q8^T
          else {
            const float* M = (s == 0) ? scr : SL(16 + s - 1);
            v = M[k * 196 + n];
          }
        } else if (n == 196 && s < 8) {
          v = gtab[s * 196 + k];
        }
      }
      f16 hi = (f16)v;
      Wph[idx] = hi;
      Wpl[idx] = (f16)(v - (float)hi);
    }
  }
}

// ---------------- capsule kernel (r5-exact: 455us verified) ----------------
__global__ __launch_bounds__(NTC, 4)
void k_caps(const float* __restrict__ x,
            const f16* __restrict__ Wph, const f16* __restrict__ Wpl,
            const float* __restrict__ d8g,
            f16* __restrict__ hbuf) {
  __shared__ __align__(16) char smem[70656];
  f16*   vAhi = (f16*)smem;                 // [64][232]
  f16*   vAlo = (f16*)(smem + 29696);       // [64][232]
  float* Sful = (float*)(smem + 59392);     // [8 i][16 elem][4 t][4 s]
  float* Rl   = (float*)(smem + 67584);     // [8 i][64 row]
  float* Cm   = (float*)(smem + 69632);     // [16 elem][4 t][4 s]

  const int tid  = threadIdx.x;
  const int w    = tid >> 6;
  const int lane = tid & 63;
  const int l15  = lane & 15;
  const int quad = lane >> 4;
  const int e0   = blockIdx.x * 16;
  const bool haveJ1 = (w + 8) < 13;

  for (int idx = tid; idx < 16 * 196; idx += NTC) {
    int elem = idx / 196, g = idx - elem * 196;
    int t = g / 49, f = (g - t * 49) * 4;
    floatx4 v4 = *(const floatx4*)&x[(size_t)(e0 + elem) * 784 + g * 4];
    half4 h4, l4;
    #pragma unroll
    for (int q = 0; q < 4; ++q) {
      f16 h = (f16)v4[q];
      h4[q] = h;
      l4[q] = (f16)(v4[q] - (float)h);
    }
    int vo = (elem * 4 + t) * 232 + f;
    *(half4*)&vAhi[vo] = h4;
    *(half4*)&vAlo[vo] = l4;
  }
  for (int p = tid; p < 64 * 36; p += NTC) {
    int row = p / 36, c = 196 + (p - (p / 36) * 36);
    vAhi[row * 232 + c] = (f16)0;
    vAlo[row * 232 + c] = (f16)0;
  }
  for (int p = tid; p < 2048; p += NTC) Sful[p] = 0.f;
  __syncthreads();

  float vv0[4][4], vv1[4][4];
  {
    int c0 = w * 16 + l15;
    int c1 = 128 + w * 16 + l15;
    #pragma unroll
    for (int mt = 0; mt < 4; ++mt)
      #pragma unroll
      for (int s = 0; s < 4; ++s) {
        int ro = ((mt * 4 + quad) * 4 + s) * 232;
        vv0[mt][s] = (float)vAhi[ro + c0] + (float)vAlo[ro + c0];
        vv1[mt][s] = haveJ1 ? ((float)vAhi[ro + c1] + (float)vAlo[ro + c1]) : 0.f;
      }
  }

  #pragma unroll 1
  for (int i = 0; i < 8; ++i) {
    floatx4 acc0[4], acc1[4];
    #pragma unroll
    for (int mt = 0; mt < 4; ++mt) {
      acc0[mt] = (floatx4){0.f, 0.f, 0.f, 0.f};
      acc1[mt] = (floatx4){0.f, 0.f, 0.f, 0.f};
    }
    const int wb0 = ((i * 208 + w * 16 + l15) * 224) + quad * 8;
    const int wb1 = ((i * 208 + (w + 8) * 16 + l15) * 224) + quad * 8;
    #pragma unroll
    for (int ks = 0; ks < 7; ++ks) {
      half8 ah[4], al[4];
      #pragma unroll
      for (int mt = 0; mt < 4; ++mt) {
        int ao = (mt * 16 + l15) * 232 + ks * 32 + quad * 8;
        ah[mt] = *(const half8*)&vAhi[ao];
        al[mt] = *(const half8*)&vAlo[ao];
      }
      {
        half8 bh = *(const half8*)&Wph[wb0 + ks * 32];
        half8 bl = *(const half8*)&Wpl[wb0 + ks * 32];
        #pragma unroll
        for (int mt = 0; mt < 4; ++mt) {
          acc0[mt] = __builtin_amdgcn_mfma_f32_16x16x32_f16(ah[mt], bh, acc0[mt], 0, 0, 0);
          acc0[mt] = __builtin_amdgcn_mfma_f32_16x16x32_f16(ah[mt], bl, acc0[mt], 0, 0, 0);
          acc0[mt] = __builtin_amdgcn_mfma_f32_16x16x32_f16(al[mt], bh, acc0[mt], 0, 0, 0);
        }
      }
      if (haveJ1) {
        half8 bh = *(const half8*)&Wph[wb1 + ks * 32];
        half8 bl = *(const half8*)&Wpl[wb1 + ks * 32];
        #pragma unroll
        for (int mt = 0; mt < 4; ++mt) {
          acc1[mt] = __builtin_amdgcn_mfma_f32_16x16x32_f16(ah[mt], bh, acc1[mt], 0, 0, 0);
          acc1[mt] = __builtin_amdgcn_mfma_f32_16x16x32_f16(ah[mt], bl, acc1[mt], 0, 0, 0);
          acc1[mt] = __builtin_amdgcn_mfma_f32_16x16x32_f16(al[mt], bh, acc1[mt], 0, 0, 0);
        }
      }
    }
    #pragma unroll
    for (int mt = 0; mt < 4; ++mt) {
      float part[16];
      #pragma unroll
      for (int t = 0; t < 4; ++t)
        #pragma unroll
        for (int s = 0; s < 4; ++s)
          part[t * 4 + s] = acc0[mt][t] * vv0[mt][s] + acc1[mt][t] * vv1[mt][s];
      #pragma unroll
      for (int p = 0; p < 16; ++p) {
        ROWSHR_ADD(part[p], 8);
        ROWSHR_ADD(part[p], 4);
        ROWSHR_ADD(part[p], 2);
        ROWSHR_ADD(part[p], 1);
      }
      if (l15 == 0) {
        int elem = mt * 4 + quad;
        #pragma unroll
        for (int t = 0; t < 4; ++t)
          #pragma unroll
          for (int s = 0; s < 4; ++s)
            atomicAdd(&Sful[((i * 16 + elem) * 4 + t) * 4 + s], part[t * 4 + s]);
      }
    }
    if (w == 4 && l15 == 4) {
      #pragma unroll
      for (int mt = 0; mt < 4; ++mt)
        *(floatx4*)&Rl[i * 64 + mt * 16 + quad * 4] = acc1[mt];
    }
  }
  __syncthreads();

  if (tid < 16) {
    const int e = tid;
    float C[4][4] = {{1,0,0,0},{0,1,0,0},{0,0,1,0},{0,0,0,1}};
    #pragma unroll 1
    for (int i = 0; i < 8; ++i) {
      float M[4][4];
      #pragma unroll
      for (int a = 0; a < 4; ++a) {
        floatx4 mm = *(const floatx4*)&Sful[((i * 16 + e) * 4 + a) * 4];
        #pragma unroll
        for (int b = 0; b < 4; ++b) M[a][b] = mm[b];
      }
      floatx4 rv = *(const floatx4*)&Rl[i * 64 + e * 4];
      float T1[4][4], Cr[4];
      #pragma unroll
      for (int t = 0; t < 4; ++t)
        #pragma unroll
        for (int b = 0; b < 4; ++b)
          T1[t][b] = C[t][0]*M[0][b] + C[t][1]*M[1][b] + C[t][2]*M[2][b] + C[t][3]*M[3][b];
      #pragma unroll
      for (int s = 0; s < 4; ++s)
        Cr[s] = C[s][0]*rv[0] + C[s][1]*rv[1] + C[s][2]*rv[2] + C[s][3]*rv[3];
      float P[4][4];
      #pragma unroll
      for (int t = 0; t < 4; ++t) {
        float S[4];
        #pragma unroll
        for (int s = 0; s < 4; ++s)
          S[s] = T1[t][0]*C[s][0] + T1[t][1]*C[s][1] + T1[t][2]*C[s][2] + T1[t][3]*C[s][3] + Cr[s];
        float m = fmaxf(fmaxf(S[0], S[1]), fmaxf(S[2], S[3]));
        float e0_ = __expf(S[0] - m), e1 = __expf(S[1] - m);
        float e2 = __expf(S[2] - m), e3 = __expf(S[3] - m);
        float inv = 1.f / (e0_ + e1 + e2 + e3);
        P[t][0] = e0_ * inv; P[t][1] = e1 * inv; P[t][2] = e2 * inv; P[t][3] = e3 * inv;
      }
      float Cn[4][4];
      #pragma unroll
      for (int t = 0; t < 4; ++t)
        #pragma unroll
        for (int s = 0; s < 4; ++s)
          Cn[t][s] = P[t][0]*C[0][s] + P[t][1]*C[1][s] + P[t][2]*C[2][s] + P[t][3]*C[3][s];
      #pragma unroll
      for (int t = 0; t < 4; ++t)
        #pragma unroll
        for (int s = 0; s < 4; ++s) C[t][s] = Cn[t][s];
    }
    #pragma unroll
    for (int t = 0; t < 4; ++t)
      *(floatx4*)&Cm[e * 16 + t * 4] = (floatx4){C[t][0], C[t][1], C[t][2], C[t][3]};
  }
  __syncthreads();

  {
    floatx4 acu0[4], acu1[4];
    #pragma unroll
    for (int mt = 0; mt < 4; ++mt) {
      acu0[mt] = (floatx4){0.f, 0.f, 0.f, 0.f};
      acu1[mt] = (floatx4){0.f, 0.f, 0.f, 0.f};
    }
    const int wb0 = ((8 * 208 + w * 16 + l15) * 224) + quad * 8;
    const int wb1 = ((8 * 208 + (w + 8) * 16 + l15) * 224) + quad * 8;
    #pragma unroll
    for (int ks = 0; ks < 7; ++ks) {
      half8 ah[4], al[4];
      #pragma unroll
      for (int mt = 0; mt < 4; ++mt) {
        int ao = (mt * 16 + l15) * 232 + ks * 32 + quad * 8;
        ah[mt] = *(const half8*)&vAhi[ao];
        al[mt] = *(const half8*)&vAlo[ao];
      }
      {
        half8 bh = *(const half8*)&Wph[wb0 + ks * 32];
        half8 bl = *(const half8*)&Wpl[wb0 + ks * 32];
        #pragma unroll
        for (int mt = 0; mt < 4; ++mt) {
          acu0[mt] = __builtin_amdgcn_mfma_f32_16x16x32_f16(ah[mt], bh, acu0[mt], 0, 0, 0);
          acu0[mt] = __builtin_amdgcn_mfma_f32_16x16x32_f16(ah[mt], bl, acu0[mt], 0, 0, 0);
          acu0[mt] = __builtin_amdgcn_mfma_f32_16x16x32_f16(al[mt], bh, acu0[mt], 0, 0, 0);
        }
      }
      if (haveJ1) {
        half8 bh = *(const half8*)&Wph[wb1 + ks * 32];
        half8 bl = *(const half8*)&Wpl[wb1 + ks * 32];
        #pragma unroll
        for (int mt = 0; mt < 4; ++mt) {
          acu1[mt] = __builtin_amdgcn_mfma_f32_16x16x32_f16(ah[mt], bh, acu1[mt], 0, 0, 0);
          acu1[mt] = __builtin_amdgcn_mfma_f32_16x16x32_f16(ah[mt], bl, acu1[mt], 0, 0, 0);
          acu1[mt] = __builtin_amdgcn_mfma_f32_16x16x32_f16(al[mt], bh, acu1[mt], 0, 0, 0);
        }
      }
    }
    const int f0 = w * 16 + l15;
    const int f1 = 128 + w * 16 + l15;
    const bool doF1 = haveJ1 && (f1 < 196);
    float d80 = d8g[f0];
    float d81 = doF1 ? d8g[f1] : 0.f;
    #pragma unroll
    for (int mt = 0; mt < 4; ++mt) {
      int elem = mt * 4 + quad;
      floatx4 c0 = *(const floatx4*)&Cm[elem * 16 + 0];
      floatx4 c1 = *(const floatx4*)&Cm[elem * 16 + 4];
      floatx4 c2 = *(const floatx4*)&Cm[elem * 16 + 8];
      floatx4 c3 = *(const floatx4*)&Cm[elem * 16 + 12];
      {
        floatx4 u = acu0[mt];
        float h0 = c0[0]*u[0] + c0[1]*u[1] + c0[2]*u[2] + c0[3]*u[3] + d80;
        float h1 = c1[0]*u[0] + c1[1]*u[1] + c1[2]*u[2] + c1[3]*u[3] + d80;
        float h2 = c2[0]*u[0] + c2[1]*u[1] + c2[2]*u[2] + c2[3]*u[3] + d80;
        float h3 = c3[0]*u[0] + c3[1]*u[1] + c3[2]*u[2] + c3[3]*u[3] + d80;
        size_t base = (size_t)(e0 + elem) * 800;
        hbuf[base + 0 * 196 + f0] = (f16)h0;
        hbuf[base + 1 * 196 + f0] = (f16)h1;
        hbuf[base + 2 * 196 + f0] = (f16)h2;
        hbuf[base + 3 * 196 + f0] = (f16)h3;
      }
      if (doF1) {
        floatx4 u = acu1[mt];
        float h0 = c0[0]*u[0] + c0[1]*u[1] + c0[2]*u[2] + c0[3]*u[3] + d81;
        float h1 = c1[0]*u[0] + c1[1]*u[1] + c1[2]*u[2] + c1[3]*u[3] + d81;
        float h2 = c2[0]*u[0] + c2[1]*u[1] + c2[2]*u[2] + c2[3]*u[3] + d81;
        float h3 = c3[0]*u[0] + c3[1]*u[1] + c3[2]*u[2] + c3[3]*u[3] + d81;
        size_t base = (size_t)(e0 + elem) * 800;
        hbuf[base + 0 * 196 + f1] = (f16)h0;
        hbuf[base + 1 * 196 + f1] = (f16)h1;
        hbuf[base + 2 * 196 + f1] = (f16)h2;
        hbuf[base + 3 * 196 + f1] = (f16)h3;
      }
    }
  }
  for (int idx = tid; idx < 256; idx += NTC)
    hbuf[(size_t)(e0 + (idx >> 4)) * 800 + 784 + (idx & 15)] = (f16)0;
}

// ---------------- decoder layer GEMM (unchanged) ----------------
__global__ __launch_bounds__(NT, 2)
void k_dec(const f16* __restrict__ A, const f16* __restrict__ Bw,
           const float* __restrict__ bias, f16* __restrict__ C, int do_relu) {
  __shared__ __align__(16) f16 As[128 * 32];
  __shared__ __align__(16) f16 Bs[128 * 32];
  const int tid = threadIdx.x, w = tid >> 6, lane = tid & 63;
  const int l15 = lane & 15, quad = lane >> 4;
  const int m0 = blockIdx.x * 128, n0 = blockIdx.y * 128;
  const int wm = w & 1, wn = w >> 1;
  const int srow = lane >> 2, soff = (lane & 3) * 8;

  floatx4 acc[4][4];
  #pragma unroll
  for (int nt = 0; nt < 4; ++nt) {
    int col = n0 + wn * 64 + nt * 16 + l15;
    float bb = (col < 784) ? bias[col] : 0.f;
    #pragma unroll
    for (int mt = 0; mt < 4; ++mt) acc[mt][nt] = (floatx4){bb, bb, bb, bb};
  }

  for (int kk = 0; kk < 25; ++kk) {
    __syncthreads();
    #pragma unroll
    for (int i = 0; i < 2; ++i) {
      int r = w * 32 + i * 16;
      glds16(&A[(size_t)(m0 + r + srow) * 800 + kk * 32 + soff], &As[r * 32]);
      glds16(&Bw[(size_t)(n0 + r + srow) * 800 + kk * 32 + soff], &Bs[r * 32]);
    }
    __syncthreads();
    half8 af[4], bf[4];
    #pragma unroll
    for (int mt = 0; mt < 4; ++mt)
      af[mt] = *(const half8*)&As[(wm * 64 + mt * 16 + l15) * 32 + quad * 8];
    #pragma unroll
    for (int nt = 0; nt < 4; ++nt)
      bf[nt] = *(const half8*)&Bs[(wn * 64 + nt * 16 + l15) * 32 + quad * 8];
    #pragma unroll
    for (int mt = 0; mt < 4; ++mt)
      #pragma unroll
      for (int nt = 0; nt < 4; ++nt)
        acc[mt][nt] = __builtin_amdgcn_mfma_f32_16x16x32_f16(af[mt], bf[nt], acc[mt][nt], 0, 0, 0);
  }

  #pragma unroll
  for (int nt = 0; nt < 4; ++nt) {
    int gcol = n0 + wn * 64 + nt * 16 + l15;
    if (gcol < 800) {
      #pragma unroll
      for (int mt = 0; mt < 4; ++mt) {
        #pragma unroll
        for (int r = 0; r < 4; ++r) {
          int grow = m0 + wm * 64 + mt * 16 + quad * 4 + r;
          float v = acc[mt][nt][r];
          if (do_relu) v = fmaxf(v, 0.f);
          C[(size_t)grow * 800 + gcol] = (f16)v;
        }
      }
    }
  }
}

// ---------------- logits + softmax (unchanged) ----------------
__global__ __launch_bounds__(NT, 4)
void k_logits(const f16* __restrict__ d2, const float* __restrict__ WoT,
              const float* __restrict__ bo, float* __restrict__ out) {
  __shared__ __align__(16) f16 ds[16 * 800];
  __shared__ float lg[160];
  const int tid = threadIdx.x;
  const size_t e0 = (size_t)blockIdx.x * 16;
  for (int i = tid; i < 16 * 98; i += NT) {
    int e = i / 98, c = (i - e * 98) * 8;
    *(half8*)&ds[e * 800 + c] = *(const half8*)&d2[(e0 + e) * 800 + c];
  }
  __syncthreads();
  {
    int e = tid >> 4, n = tid & 15;
    const f16* dp = &ds[e * 800];
    float s = 0.f;
    #pragma unroll 4
    for (int f = 0; f < 784; ++f) s += (float)dp[f] * WoT[f * 16 + n];
    if (n < 10) lg[e * 10 + n] = s + bo[n];
  }
  __syncthreads();
  if (tid < 16) {
    float l[10], m = -1e30f;
    #pragma unroll
    for (int n = 0; n < 10; ++n) { l[n] = lg[tid * 10 + n]; m = fmaxf(m, l[n]); }
    float sum = 0.f;
    #pragma unroll
    for (int n = 0; n < 10; ++n) { l[n] = __expf(l[n] - m); sum += l[n]; }
    float inv = 1.f / sum;
    #pragma unroll
    for (int n = 0; n < 10; ++n) out[(e0 + tid) * 10 + n] = l[n] * inv;
  }
}

extern "C" void kernel_launch(void* const* d_in, const int* in_sizes, int n_in,
                              void* d_out, int out_size, void* d_ws, size_t ws_size,
                              hipStream_t stream) {
  const float* x   = (const float*)d_in[0];
  const float* W1  = (const float*)d_in[1];
  const float* b1  = (const float*)d_in[2];
  const float* W2  = (const float*)d_in[3];
  // b2 (d_in[4]) cancels in the softmax (row-constant) — unused.
  const float* W3  = (const float*)d_in[5];
  const float* b3  = (const float*)d_in[6];
  const float* Wd1 = (const float*)d_in[7];
  const float* bd1 = (const float*)d_in[8];
  const float* Wd2 = (const float*)d_in[9];
  const float* bd2 = (const float*)d_in[10];
  const float* Wo  = (const float*)d_in[11];
  const float* bo  = (const float*)d_in[12];
  float* out = (float*)d_out;

  char* ws = (char*)d_ws;
  f16*   Wd1p  = (f16*)(ws + WD1_OFF);
  f16*   Wd2p  = (f16*)(ws + WD2_OFF);
  float* WoTws = (float*)(ws + WOT_OFF);
  float* d8ws  = (float*)(ws + D8_OFF);
  f16*   hbuf  = (f16*)(ws + HBUF_OFF);
  f16*   d1buf = (f16*)(ws + D1_OFF);
  f16*   Wph   = (f16*)(ws + WPKH_OFF);
  f16*   Wpl   = (f16*)(ws + WPKL_OFF);
  float* scr   = (float*)(ws + HBUF_OFF);   // fp32 prep scratch, dead before k_caps writes hbuf

  k_prep_wd<<<(896 * 800 + NT - 1) / NT, NT, 0, stream>>>(Wd1, Wd1p);
  k_prep_wd<<<(896 * 800 + NT - 1) / NT, NT, 0, stream>>>(Wd2, Wd2p);
  k_prep_wo<<<(784 * 16 + NT - 1) / NT, NT, 0, stream>>>(Wo, WoTws);

  // whole capsule prep in ONE cooperative launch (6 grid-synced stages)
  void* kargs[] = {(void*)&W1, (void*)&W2, (void*)&W3, (void*)&b1, (void*)&b3,
                   (void*)&scr, (void*)&d8ws, (void*)&Wph, (void*)&Wpl};
  hipLaunchCooperativeKernel((void*)k_prep_all, dim3(1024), dim3(NT), kargs, 0, stream);

  k_caps<<<32768 / 16, NTC, 0, stream>>>(x, Wph, Wpl, d8ws, hbuf);
  k_dec<<<dim3(32768 / 128, 7), NT, 0, stream>>>(hbuf, Wd1p, bd1, d1buf, 1);
  k_dec<<<dim3(32768 / 128, 7), NT, 0, stream>>>(d1buf, Wd2p, bd2, hbuf, 0);
  k_logits<<<32768 / 16, NT, 0, stream>>>(hbuf, WoTws, bo, out);
}

// Round 8
// 1028.067 us; speedup vs baseline: 1.4648x; 1.4648x over previous
//
#include <hip/hip_runtime.h>
#include <math.h>

#define NT 256
#define NTC 512
typedef _Float16 f16;
typedef _Float16 half8 __attribute__((ext_vector_type(8)));
typedef _Float16 half4 __attribute__((ext_vector_type(4)));
typedef float floatx4 __attribute__((ext_vector_type(4)));

// DPP row_shr sum (VALU-only reduce within 16-lane rows; full sum valid at l15==0 — HW-verified r3)
#define ROWSHR_ADD(v, N) \
  (v) += __int_as_float(__builtin_amdgcn_update_dpp(0, __float_as_int(v), 0x110 | (N), 0xF, 0xF, true))

// ---------------- workspace layout (bytes) ----------------
#define WD1_OFF  0              // 896*800*2 = 1433600
#define WD2_OFF  1433600        // -> 2867200
#define WOT_OFF  2867200        // WoT [16][800] f32 = 51200 -> 2918400
#define D8_OFF   2918400        // 196*4 (pad 1024) -> 2919424
#define HBUF_OFF 2919424        // 32768*800*2 = 52428800 -> 55348224
#define D1_OFF   55348224       // 52428800 -> end ~107.8MB
#define WPKH_OFF 55348224       // 9*208*224*2 = 838656 (inside d1, dead before k_dec#1)
#define WPKL_OFF 56186880
#define SSE      38464          // scratch slot stride in floats (>=196*196)
// scratch slots (floats @ hbuf base, dead before k_caps writes hbuf):
// 0:G  1..8:Q_1..Q_8 (Q_i=W3^i; K_i=Q_i^T)  9..15:T_1..7  16..22:H_1..7  23:gtab(8*196)

__device__ inline void glds16(const void* g, void* l) {
  __builtin_amdgcn_global_load_lds((const __attribute__((address_space(1))) void*)g,
                                   (__attribute__((address_space(3))) void*)l, 16, 0, 0);
}

// ---------------- prep: merged decoder/output weights (one launch) ----------------
__global__ void k_prep_io(const float* __restrict__ Wd1, const float* __restrict__ Wd2,
                          const float* __restrict__ Wo,
                          f16* __restrict__ W1p, f16* __restrict__ W2p,
                          float* __restrict__ WoT) {
  int b = blockIdx.x;
  if (b < 5600) {
    const float* Wd = (b < 2800) ? Wd1 : Wd2;
    f16* W16 = (b < 2800) ? W1p : W2p;
    int idx = (b % 2800) * NT + threadIdx.x;
    if (idx < 896 * 800) {
      int n = idx / 800, k = idx - n * 800;
      W16[idx] = (f16)((n < 784 && k < 784) ? Wd[n * 784 + k] : 0.f);
    }
  } else {
    int idx = (b - 5600) * NT + threadIdx.x;
    if (idx < 16 * 800) {
      int n = idx / 800, f = idx - n * 800;
      WoT[idx] = (n < 10 && f < 784) ? Wo[n * 784 + f] : 0.f;   // [16][800] row-major
    }
  }
}

// ---------------- prep: level-1 — G = W1^T W2 ; Q2 = W3 W3 ; Q1 = copy(W3) ----------------
__global__ void k_prep_gq(const float* __restrict__ W1, const float* __restrict__ W2,
                          const float* __restrict__ W3, float* __restrict__ scr) {
  __shared__ float red[256];
  const int tid = threadIdx.x;
  int b = blockIdx.x;
  if (b < 1202) {
    int ta = (b < 601);
    const float* A = ta ? W1 : W3;
    const float* B = ta ? W2 : W3;
    float* C = ta ? scr : (scr + (size_t)2 * SSE);
    int u = ta ? b : (b - 601);
    int o = u * 64 + (tid & 63);
    int ks = tid >> 6;
    float s = 0.f;
    int p = 0, r = 0;
    if (o < 38416) {
      p = o / 196; r = o - p * 196;
      const int c0 = ks * 49;
      #pragma unroll 7
      for (int c = c0; c < c0 + 49; ++c) {
        float a = ta ? A[c * 196 + p] : A[p * 196 + c];
        s += a * B[c * 196 + r];
      }
    }
    red[tid] = s;
    __syncthreads();
    if (tid < 64 && o < 38416)
      C[p * 196 + r] = red[tid] + red[tid + 64] + red[tid + 128] + red[tid + 192];
  } else {
    int idx = (b - 1202) * NT + tid;
    if (idx < 38416) scr[(size_t)SSE + idx] = W3[idx];
  }
}

// ---------------- prep: table-driven batched 196x196 products (stages 0..3) ----------------
// L0: Q3,Q4,T1,T2     L1: Q5..Q8,T3,T4,H1,H2     L2: T5,T6,T7,H3,H4 (+vec at y==5)   L3: H5,H6,H7
__constant__ int MMA[4][8] = {{2,2,1,2,0,0,0,0},{4,4,4,4,3,4,9,10},
                              {5,6,7,11,12,0,0,0},{13,14,15,0,0,0,0,0}};
__constant__ int MMB[4][8] = {{1,2,0,0,0,0,0,0},{1,2,3,4,0,0,1,2},
                              {0,0,0,3,4,0,0,0},{5,6,7,0,0,0,0,0}};
__constant__ int MMC[4][8] = {{3,4,9,10,0,0,0,0},{5,6,7,8,11,12,16,17},
                              {13,14,15,18,19,0,0,0},{20,21,22,0,0,0,0,0}};
__constant__ int MMT[4][8] = {{0,0,1,1,0,0,0,0},{0,0,0,0,1,1,0,0},
                              {1,1,1,0,0,0,0,0},{0,0,0,0,0,0,0,0}};

__global__ __launch_bounds__(NT, 4)
void k_mmb(float* __restrict__ scr, int stage,
           const float* __restrict__ W2, const float* __restrict__ b1,
           const float* __restrict__ b3, float* __restrict__ d8out) {
  __shared__ float red[256];
  __shared__ float z[196], cj[196], dd[196], tmp[196];
  const int tid = threadIdx.x;
  const int y = blockIdx.y;

  if (stage == 2 && y == 5) {
    // ---- vectors: one block per i (c-chain, d_i, g_i, ghat_i, d8) ----
    if (blockIdx.x >= 8) return;
    const int i = blockIdx.x;
    const float* G = scr;
    const float* Qbase = scr + (size_t)SSE;
    float* gtab = scr + (size_t)23 * SSE;
    const float* W3c = Qbase;              // Q1 slot = W3 copy
    for (int t = tid; t < 196; t += NT) {
      float s = 0.f;
      for (int f = 0; f < 196; ++f) s += b1[f] * W2[f * 196 + t];
      z[t] = s; dd[t] = 0.f; cj[t] = b3[t];
    }
    __syncthreads();
    for (int j = 0; j < i; ++j) {
      for (int t = tid; t < 196; t += NT) {
        float s = 0.f;
        for (int c = 0; c < 196; ++c) s += W3c[t * 196 + c] * cj[c];
        tmp[t] = s; dd[t] += cj[t];
      }
      __syncthreads();
      for (int t = tid; t < 196; t += NT) cj[t] = tmp[t];
      __syncthreads();
    }
    if (i == 7)
      for (int t = tid; t < 196; t += NT) d8out[t] = dd[t] + cj[t];
    for (int t = tid; t < 196; t += NT) {
      float s = z[t];
      for (int k = 0; k < 196; ++k) s += G[k * 196 + t] * dd[k];
      tmp[t] = s;
    }
    __syncthreads();
    for (int t = tid; t < 196; t += NT) {
      float s;
      if (i == 0) s = tmp[t];
      else {
        const float* Qi = Qbase + (size_t)(i - 1) * SSE;
        s = 0.f;
        for (int n = 0; n < 196; ++n) s += Qi[n * 196 + t] * tmp[n];
      }
      gtab[i * 196 + t] = s;
    }
    return;
  }

  const float* A = scr + (size_t)MMA[stage][y] * SSE;
  const float* B = scr + (size_t)MMB[stage][y] * SSE;
  float*       C = scr + (size_t)MMC[stage][y] * SSE;
  const int ta = MMT[stage][y];
  int o = blockIdx.x * 64 + (tid & 63);
  int ks = tid >> 6;
  float s = 0.f;
  int p = 0, r = 0;
  if (o < 38416) {
    p = o / 196; r = o - p * 196;
    const int c0 = ks * 49;
    #pragma unroll 7
    for (int c = c0; c < c0 + 49; ++c) {
      float a = ta ? A[c * 196 + p] : A[p * 196 + c];
      s += a * B[c * 196 + r];
    }
  }
  red[tid] = s;
  __syncthreads();
  if (tid < 64 && o < 38416)
    C[p * 196 + r] = red[tid] + red[tid + 64] + red[tid + 128] + red[tid + 192];
}

// ---------------- prep: pack Wpk[9 slots][208 n][224 k] f16 hi/lo ----------------
__global__ void k_prep_pack(const float* __restrict__ scr,
                            f16* __restrict__ Wph, f16* __restrict__ Wpl) {
  int idx = blockIdx.x * NT + threadIdx.x;
  if (idx >= 9 * 208 * 224) return;
  int s = idx / (208 * 224), rem = idx - s * (208 * 224);
  int n = rem / 224, k = rem - n * 224;
  float v = 0.f;
  if (k < 196) {
    if (n < 196) {
      if (s == 8) v = scr[(size_t)8 * SSE + n * 196 + k];       // K8 = Q8^T
      else {
        const float* M = (s == 0) ? scr : (scr + (size_t)(16 + s - 1) * SSE);
        v = M[k * 196 + n];
      }
    } else if (n == 196 && s < 8) {
      v = scr[(size_t)23 * SSE + s * 196 + k];
    }
  }
  f16 hi = (f16)v;
  Wph[idx] = hi;
  Wpl[idx] = (f16)(v - (float)hi);
}

// ---------------- capsule kernel (r5-exact: 455us verified) ----------------
__global__ __launch_bounds__(NTC, 4)
void k_caps(const float* __restrict__ x,
            const f16* __restrict__ Wph, const f16* __restrict__ Wpl,
            const float* __restrict__ d8g,
            f16* __restrict__ hbuf) {
  __shared__ __align__(16) char smem[70656];
  f16*   vAhi = (f16*)smem;                 // [64][232]
  f16*   vAlo = (f16*)(smem + 29696);       // [64][232]
  float* Sful = (float*)(smem + 59392);     // [8 i][16 elem][4 t][4 s]
  float* Rl   = (float*)(smem + 67584);     // [8 i][64 row]
  float* Cm   = (float*)(smem + 69632);     // [16 elem][4 t][4 s]

  const int tid  = threadIdx.x;
  const int w    = tid >> 6;
  const int lane = tid & 63;
  const int l15  = lane & 15;
  const int quad = lane >> 4;
  const int e0   = blockIdx.x * 16;
  const bool haveJ1 = (w + 8) < 13;

  for (int idx = tid; idx < 16 * 196; idx += NTC) {
    int elem = idx / 196, g = idx - elem * 196;
    int t = g / 49, f = (g - t * 49) * 4;
    floatx4 v4 = *(const floatx4*)&x[(size_t)(e0 + elem) * 784 + g * 4];
    half4 h4, l4;
    #pragma unroll
    for (int q = 0; q < 4; ++q) {
      f16 h = (f16)v4[q];
      h4[q] = h;
      l4[q] = (f16)(v4[q] - (float)h);
    }
    int vo = (elem * 4 + t) * 232 + f;
    *(half4*)&vAhi[vo] = h4;
    *(half4*)&vAlo[vo] = l4;
  }
  for (int p = tid; p < 64 * 36; p += NTC) {
    int row = p / 36, c = 196 + (p - (p / 36) * 36);
    vAhi[row * 232 + c] = (f16)0;
    vAlo[row * 232 + c] = (f16)0;
  }
  for (int p = tid; p < 2048; p += NTC) Sful[p] = 0.f;
  __syncthreads();

  float vv0[4][4], vv1[4][4];
  {
    int c0 = w * 16 + l15;
    int c1 = 128 + w * 16 + l15;
    #pragma unroll
    for (int mt = 0; mt < 4; ++mt)
      #pragma unroll
      for (int s = 0; s < 4; ++s) {
        int ro = ((mt * 4 + quad) * 4 + s) * 232;
        vv0[mt][s] = (float)vAhi[ro + c0] + (float)vAlo[ro + c0];
        vv1[mt][s] = haveJ1 ? ((float)vAhi[ro + c1] + (float)vAlo[ro + c1]) : 0.f;
      }
  }

  #pragma unroll 1
  for (int i = 0; i < 8; ++i) {
    floatx4 acc0[4], acc1[4];
    #pragma unroll
    for (int mt = 0; mt < 4; ++mt) {
      acc0[mt] = (floatx4){0.f, 0.f, 0.f, 0.f};
      acc1[mt] = (floatx4){0.f, 0.f, 0.f, 0.f};
    }
    const int wb0 = ((i * 208 + w * 16 + l15) * 224) + quad * 8;
    const int wb1 = ((i * 208 + (w + 8) * 16 + l15) * 224) + quad * 8;
    #pragma unroll
    for (int ks = 0; ks < 7; ++ks) {
      half8 ah[4], al[4];
      #pragma unroll
      for (int mt = 0; mt < 4; ++mt) {
        int ao = (mt * 16 + l15) * 232 + ks * 32 + quad * 8;
        ah[mt] = *(const half8*)&vAhi[ao];
        al[mt] = *(const half8*)&vAlo[ao];
      }
      {
        half8 bh = *(const half8*)&Wph[wb0 + ks * 32];
        half8 bl = *(const half8*)&Wpl[wb0 + ks * 32];
        #pragma unroll
        for (int mt = 0; mt < 4; ++mt) {
          acc0[mt] = __builtin_amdgcn_mfma_f32_16x16x32_f16(ah[mt], bh, acc0[mt], 0, 0, 0);
          acc0[mt] = __builtin_amdgcn_mfma_f32_16x16x32_f16(ah[mt], bl, acc0[mt], 0, 0, 0);
          acc0[mt] = __builtin_amdgcn_mfma_f32_16x16x32_f16(al[mt], bh, acc0[mt], 0, 0, 0);
        }
      }
      if (haveJ1) {
        half8 bh = *(const half8*)&Wph[wb1 + ks * 32];
        half8 bl = *(const half8*)&Wpl[wb1 + ks * 32];
        #pragma unroll
        for (int mt = 0; mt < 4; ++mt) {
          acc1[mt] = __builtin_amdgcn_mfma_f32_16x16x32_f16(ah[mt], bh, acc1[mt], 0, 0, 0);
          acc1[mt] = __builtin_amdgcn_mfma_f32_16x16x32_f16(ah[mt], bl, acc1[mt], 0, 0, 0);
          acc1[mt] = __builtin_amdgcn_mfma_f32_16x16x32_f16(al[mt], bh, acc1[mt], 0, 0, 0);
        }
      }
    }
    #pragma unroll
    for (int mt = 0; mt < 4; ++mt) {
      float part[16];
      #pragma unroll
      for (int t = 0; t < 4; ++t)
        #pragma unroll
        for (int s = 0; s < 4; ++s)
          part[t * 4 + s] = acc0[mt][t] * vv0[mt][s] + acc1[mt][t] * vv1[mt][s];
      #pragma unroll
      for (int p = 0; p < 16; ++p) {
        ROWSHR_ADD(part[p], 8);
        ROWSHR_ADD(part[p], 4);
        ROWSHR_ADD(part[p], 2);
        ROWSHR_ADD(part[p], 1);
      }
      if (l15 == 0) {
        int elem = mt * 4 + quad;
        #pragma unroll
        for (int t = 0; t < 4; ++t)
          #pragma unroll
          for (int s = 0; s < 4; ++s)
            atomicAdd(&Sful[((i * 16 + elem) * 4 + t) * 4 + s], part[t * 4 + s]);
      }
    }
    if (w == 4 && l15 == 4) {
      #pragma unroll
      for (int mt = 0; mt < 4; ++mt)
        *(floatx4*)&Rl[i * 64 + mt * 16 + quad * 4] = acc1[mt];
    }
  }
  __syncthreads();

  if (tid < 16) {
    const int e = tid;
    float C[4][4] = {{1,0,0,0},{0,1,0,0},{0,0,1,0},{0,0,0,1}};
    #pragma unroll 1
    for (int i = 0; i < 8; ++i) {
      float M[4][4];
      #pragma unroll
      for (int a = 0; a < 4; ++a) {
        floatx4 mm = *(const floatx4*)&Sful[((i * 16 + e) * 4 + a) * 4];
        #pragma unroll
        for (int b = 0; b < 4; ++b) M[a][b] = mm[b];
      }
      floatx4 rv = *(const floatx4*)&Rl[i * 64 + e * 4];
      float T1[4][4], Cr[4];
      #pragma unroll
      for (int t = 0; t < 4; ++t)
        #pragma unroll
        for (int b = 0; b < 4; ++b)
          T1[t][b] = C[t][0]*M[0][b] + C[t][1]*M[1][b] + C[t][2]*M[2][b] + C[t][3]*M[3][b];
      #pragma unroll
      for (int s = 0; s < 4; ++s)
        Cr[s] = C[s][0]*rv[0] + C[s][1]*rv[1] + C[s][2]*rv[2] + C[s][3]*rv[3];
      float P[4][4];
      #pragma unroll
      for (int t = 0; t < 4; ++t) {
        float S[4];
        #pragma unroll
        for (int s = 0; s < 4; ++s)
          S[s] = T1[t][0]*C[s][0] + T1[t][1]*C[s][1] + T1[t][2]*C[s][2] + T1[t][3]*C[s][3] + Cr[s];
        float m = fmaxf(fmaxf(S[0], S[1]), fmaxf(S[2], S[3]));
        float e0_ = __expf(S[0] - m), e1 = __expf(S[1] - m);
        float e2 = __expf(S[2] - m), e3 = __expf(S[3] - m);
        float inv = 1.f / (e0_ + e1 + e2 + e3);
        P[t][0] = e0_ * inv; P[t][1] = e1 * inv; P[t][2] = e2 * inv; P[t][3] = e3 * inv;
      }
      float Cn[4][4];
      #pragma unroll
      for (int t = 0; t < 4; ++t)
        #pragma unroll
        for (int s = 0; s < 4; ++s)
          Cn[t][s] = P[t][0]*C[0][s] + P[t][1]*C[1][s] + P[t][2]*C[2][s] + P[t][3]*C[3][s];
      #pragma unroll
      for (int t = 0; t < 4; ++t)
        #pragma unroll
        for (int s = 0; s < 4; ++s) C[t][s] = Cn[t][s];
    }
    #pragma unroll
    for (int t = 0; t < 4; ++t)
      *(floatx4*)&Cm[e * 16 + t * 4] = (floatx4){C[t][0], C[t][1], C[t][2], C[t][3]};
  }
  __syncthreads();

  {
    floatx4 acu0[4], acu1[4];
    #pragma unroll
    for (int mt = 0; mt < 4; ++mt) {
      acu0[mt] = (floatx4){0.f, 0.f, 0.f, 0.f};
      acu1[mt] = (floatx4){0.f, 0.f, 0.f, 0.f};
    }
    const int wb0 = ((8 * 208 + w * 16 + l15) * 224) + quad * 8;
    const int wb1 = ((8 * 208 + (w + 8) * 16 + l15) * 224) + quad * 8;
    #pragma unroll
    for (int ks = 0; ks < 7; ++ks) {
      half8 ah[4], al[4];
      #pragma unroll
      for (int mt = 0; mt < 4; ++mt) {
        int ao = (mt * 16 + l15) * 232 + ks * 32 + quad * 8;
        ah[mt] = *(const half8*)&vAhi[ao];
        al[mt] = *(const half8*)&vAlo[ao];
      }
      {
        half8 bh = *(const half8*)&Wph[wb0 + ks * 32];
        half8 bl = *(const half8*)&Wpl[wb0 + ks * 32];
        #pragma unroll
        for (int mt = 0; mt < 4; ++mt) {
          acu0[mt] = __builtin_amdgcn_mfma_f32_16x16x32_f16(ah[mt], bh, acu0[mt], 0, 0, 0);
          acu0[mt] = __builtin_amdgcn_mfma_f32_16x16x32_f16(ah[mt], bl, acu0[mt], 0, 0, 0);
          acu0[mt] = __builtin_amdgcn_mfma_f32_16x16x32_f16(al[mt], bh, acu0[mt], 0, 0, 0);
        }
      }
      if (haveJ1) {
        half8 bh = *(const half8*)&Wph[wb1 + ks * 32];
        half8 bl = *(const half8*)&Wpl[wb1 + ks * 32];
        #pragma unroll
        for (int mt = 0; mt < 4; ++mt) {
          acu1[mt] = __builtin_amdgcn_mfma_f32_16x16x32_f16(ah[mt], bh, acu1[mt], 0, 0, 0);
          acu1[mt] = __builtin_amdgcn_mfma_f32_16x16x32_f16(ah[mt], bl, acu1[mt], 0, 0, 0);
          acu1[mt] = __builtin_amdgcn_mfma_f32_16x16x32_f16(al[mt], bh, acu1[mt], 0, 0, 0);
        }
      }
    }
    const int f0 = w * 16 + l15;
    const int f1 = 128 + w * 16 + l15;
    const bool doF1 = haveJ1 && (f1 < 196);
    float d80 = d8g[f0];
    float d81 = doF1 ? d8g[f1] : 0.f;
    #pragma unroll
    for (int mt = 0; mt < 4; ++mt) {
      int elem = mt * 4 + quad;
      floatx4 c0 = *(const floatx4*)&Cm[elem * 16 + 0];
      floatx4 c1 = *(const floatx4*)&Cm[elem * 16 + 4];
      floatx4 c2 = *(const floatx4*)&Cm[elem * 16 + 8];
      floatx4 c3 = *(const floatx4*)&Cm[elem * 16 + 12];
      {
        floatx4 u = acu0[mt];
        float h0 = c0[0]*u[0] + c0[1]*u[1] + c0[2]*u[2] + c0[3]*u[3] + d80;
        float h1 = c1[0]*u[0] + c1[1]*u[1] + c1[2]*u[2] + c1[3]*u[3] + d80;
        float h2 = c2[0]*u[0] + c2[1]*u[1] + c2[2]*u[2] + c2[3]*u[3] + d80;
        float h3 = c3[0]*u[0] + c3[1]*u[1] + c3[2]*u[2] + c3[3]*u[3] + d80;
        size_t base = (size_t)(e0 + elem) * 800;
        hbuf[base + 0 * 196 + f0] = (f16)h0;
        hbuf[base + 1 * 196 + f0] = (f16)h1;
        hbuf[base + 2 * 196 + f0] = (f16)h2;
        hbuf[base + 3 * 196 + f0] = (f16)h3;
      }
      if (doF1) {
        floatx4 u = acu1[mt];
        float h0 = c0[0]*u[0] + c0[1]*u[1] + c0[2]*u[2] + c0[3]*u[3] + d81;
        float h1 = c1[0]*u[0] + c1[1]*u[1] + c1[2]*u[2] + c1[3]*u[3] + d81;
        float h2 = c2[0]*u[0] + c2[1]*u[1] + c2[2]*u[2] + c2[3]*u[3] + d81;
        float h3 = c3[0]*u[0] + c3[1]*u[1] + c3[2]*u[2] + c3[3]*u[3] + d81;
        size_t base = (size_t)(e0 + elem) * 800;
        hbuf[base + 0 * 196 + f1] = (f16)h0;
        hbuf[base + 1 * 196 + f1] = (f16)h1;
        hbuf[base + 2 * 196 + f1] = (f16)h2;
        hbuf[base + 3 * 196 + f1] = (f16)h3;
      }
    }
  }
  for (int idx = tid; idx < 256; idx += NTC)
    hbuf[(size_t)(e0 + (idx >> 4)) * 800 + 784 + (idx & 15)] = (f16)0;
}

// ---------------- decoder layer GEMM (occupancy 2->4 blocks/CU) ----------------
__global__ __launch_bounds__(NT, 4)
void k_dec(const f16* __restrict__ A, const f16* __restrict__ Bw,
           const float* __restrict__ bias, f16* __restrict__ C, int do_relu) {
  __shared__ __align__(16) f16 As[128 * 32];
  __shared__ __align__(16) f16 Bs[128 * 32];
  const int tid = threadIdx.x, w = tid >> 6, lane = tid & 63;
  const int l15 = lane & 15, quad = lane >> 4;
  const int m0 = blockIdx.x * 128, n0 = blockIdx.y * 128;
  const int wm = w & 1, wn = w >> 1;
  const int srow = lane >> 2, soff = (lane & 3) * 8;

  floatx4 acc[4][4];
  #pragma unroll
  for (int nt = 0; nt < 4; ++nt) {
    int col = n0 + wn * 64 + nt * 16 + l15;
    float bb = (col < 784) ? bias[col] : 0.f;
    #pragma unroll
    for (int mt = 0; mt < 4; ++mt) acc[mt][nt] = (floatx4){bb, bb, bb, bb};
  }

  for (int kk = 0; kk < 25; ++kk) {
    __syncthreads();
    #pragma unroll
    for (int i = 0; i < 2; ++i) {
      int r = w * 32 + i * 16;
      glds16(&A[(size_t)(m0 + r + srow) * 800 + kk * 32 + soff], &As[r * 32]);
      glds16(&Bw[(size_t)(n0 + r + srow) * 800 + kk * 32 + soff], &Bs[r * 32]);
    }
    __syncthreads();
    half8 af[4], bf[4];
    #pragma unroll
    for (int mt = 0; mt < 4; ++mt)
      af[mt] = *(const half8*)&As[(wm * 64 + mt * 16 + l15) * 32 + quad * 8];
    #pragma unroll
    for (int nt = 0; nt < 4; ++nt)
      bf[nt] = *(const half8*)&Bs[(wn * 64 + nt * 16 + l15) * 32 + quad * 8];
    #pragma unroll
    for (int mt = 0; mt < 4; ++mt)
      #pragma unroll
      for (int nt = 0; nt < 4; ++nt)
        acc[mt][nt] = __builtin_amdgcn_mfma_f32_16x16x32_f16(af[mt], bf[nt], acc[mt][nt], 0, 0, 0);
  }

  #pragma unroll
  for (int nt = 0; nt < 4; ++nt) {
    int gcol = n0 + wn * 64 + nt * 16 + l15;
    if (gcol < 800) {
      #pragma unroll
      for (int mt = 0; mt < 4; ++mt) {
        #pragma unroll
        for (int r = 0; r < 4; ++r) {
          int grow = m0 + wm * 64 + mt * 16 + quad * 4 + r;
          float v = acc[mt][nt][r];
          if (do_relu) v = fmaxf(v, 0.f);
          C[(size_t)grow * 800 + gcol] = (f16)v;
        }
      }
    }
  }
}

// ---------------- logits + softmax (WoT transposed [16][800], vector loads) ----------------
__global__ __launch_bounds__(NT, 4)
void k_logits(const f16* __restrict__ d2, const float* __restrict__ WoT,
              const float* __restrict__ bo, float* __restrict__ out) {
  __shared__ __align__(16) f16 ds[16 * 800];
  __shared__ float lg[160];
  const int tid = threadIdx.x;
  const size_t e0 = (size_t)blockIdx.x * 16;
  for (int i = tid; i < 16 * 98; i += NT) {
    int e = i / 98, c = (i - e * 98) * 8;
    *(half8*)&ds[e * 800 + c] = *(const half8*)&d2[(e0 + e) * 800 + c];
  }
  __syncthreads();
  {
    int e = tid >> 4, n = tid & 15;
    const f16* dp = &ds[e * 800];
    const float* wt = &WoT[n * 800];
    float s = 0.f;
    #pragma unroll 2
    for (int f = 0; f < 784; f += 8) {
      half8 d8 = *(const half8*)&dp[f];
      floatx4 wa = *(const floatx4*)&wt[f];
      floatx4 wb = *(const floatx4*)&wt[f + 4];
      s += (float)d8[0]*wa[0] + (float)d8[1]*wa[1] + (float)d8[2]*wa[2] + (float)d8[3]*wa[3]
         + (float)d8[4]*wb[0] + (float)d8[5]*wb[1] + (float)d8[6]*wb[2] + (float)d8[7]*wb[3];
    }
    if (n < 10) lg[e * 10 + n] = s + bo[n];
  }
  __syncthreads();
  if (tid < 16) {
    float l[10], m = -1e30f;
    #pragma unroll
    for (int n = 0; n < 10; ++n) { l[n] = lg[tid * 10 + n]; m = fmaxf(m, l[n]); }
    float sum = 0.f;
    #pragma unroll
    for (int n = 0; n < 10; ++n) { l[n] = __expf(l[n] - m); sum += l[n]; }
    float inv = 1.f / sum;
    #pragma unroll
    for (int n = 0; n < 10; ++n) out[(e0 + tid) * 10 + n] = l[n] * inv;
  }
}

extern "C" void kernel_launch(void* const* d_in, const int* in_sizes, int n_in,
                              void* d_out, int out_size, void* d_ws, size_t ws_size,
                              hipStream_t stream) {
  const float* x   = (const float*)d_in[0];
  const float* W1  = (const float*)d_in[1];
  const float* b1  = (const float*)d_in[2];
  const float* W2  = (const float*)d_in[3];
  // b2 (d_in[4]) cancels in the softmax (row-constant) — unused.
  const float* W3  = (const float*)d_in[5];
  const float* b3  = (const float*)d_in[6];
  const float* Wd1 = (const float*)d_in[7];
  const float* bd1 = (const float*)d_in[8];
  const float* Wd2 = (const float*)d_in[9];
  const float* bd2 = (const float*)d_in[10];
  const float* Wo  = (const float*)d_in[11];
  const float* bo  = (const float*)d_in[12];
  float* out = (float*)d_out;

  char* ws = (char*)d_ws;
  f16*   Wd1p  = (f16*)(ws + WD1_OFF);
  f16*   Wd2p  = (f16*)(ws + WD2_OFF);
  float* WoTws = (float*)(ws + WOT_OFF);
  float* d8ws  = (float*)(ws + D8_OFF);
  f16*   hbuf  = (f16*)(ws + HBUF_OFF);
  f16*   d1buf = (f16*)(ws + D1_OFF);
  f16*   Wph   = (f16*)(ws + WPKH_OFF);
  f16*   Wpl   = (f16*)(ws + WPKL_OFF);
  float* scr   = (float*)(ws + HBUF_OFF);   // fp32 prep scratch, dead before k_caps writes hbuf

  // merged IO prep (wd1, wd2, wo-transposed) — one launch
  k_prep_io<<<5650, NT, 0, stream>>>(Wd1, Wd2, Wo, Wd1p, Wd2p, WoTws);
  // level-1: G, Q2, Q1-copy — one launch
  k_prep_gq<<<1353, NT, 0, stream>>>(W1, W2, W3, scr);
  // levels 2..5: table-driven batched products (+vec folded into stage 2)
  k_mmb<<<dim3(601, 4), NT, 0, stream>>>(scr, 0, W2, b1, b3, d8ws);
  k_mmb<<<dim3(601, 8), NT, 0, stream>>>(scr, 1, W2, b1, b3, d8ws);
  k_mmb<<<dim3(601, 6), NT, 0, stream>>>(scr, 2, W2, b1, b3, d8ws);
  k_mmb<<<dim3(601, 3), NT, 0, stream>>>(scr, 3, W2, b1, b3, d8ws);
  // pack f16 hi/lo weight block
  k_prep_pack<<<(9 * 208 * 224 + NT - 1) / NT, NT, 0, stream>>>(scr, Wph, Wpl);

  k_caps<<<32768 / 16, NTC, 0, stream>>>(x, Wph, Wpl, d8ws, hbuf);
  k_dec<<<dim3(32768 / 128, 7), NT, 0, stream>>>(hbuf, Wd1p, bd1, d1buf, 1);
  k_dec<<<dim3(32768 / 128, 7), NT, 0, stream>>>(d1buf, Wd2p, bd2, hbuf, 0);
  k_logits<<<32768 / 16, NT, 0, stream>>>(hbuf, WoTws, bo, out);
}

// Round 9
// 889.693 us; speedup vs baseline: 1.6926x; 1.1555x over previous
//
#include <hip/hip_runtime.h>
#include <math.h>

#define NT 256
#define NTC 512
typedef _Float16 f16;
typedef _Float16 half8 __attribute__((ext_vector_type(8)));
typedef _Float16 half4 __attribute__((ext_vector_type(4)));
typedef float floatx4 __attribute__((ext_vector_type(4)));

// DPP row_shr sum (VALU-only reduce within 16-lane rows; full sum valid at l15==0 — HW-verified r3)
#define ROWSHR_ADD(v, N) \
  (v) += __int_as_float(__builtin_amdgcn_update_dpp(0, __float_as_int(v), 0x110 | (N), 0xF, 0xF, true))

// ---------------- workspace layout (bytes) ----------------
#define WD1_OFF  0              // 896*800*2 = 1433600
#define WD2_OFF  1433600        // -> 2867200
#define WOT_OFF  2867200        // WoT [784][16] f32 = 50176 -> 2918400 (padded)
#define D8_OFF   2918400        // 196*4 (pad 1024) -> 2919424
#define HBUF_OFF 2919424        // 32768*800*2 = 52428800 -> 55348224
#define D1_OFF   55348224       // 52428800 -> end ~107.8MB
#define WPKH_OFF 55348224       // 9*208*224*2 = 838656 (inside d1, dead before k_dec#1)
#define WPKL_OFF 56186880
#define SSE      38464          // scratch slot stride in floats (>=196*196)
// scratch slots (floats @ hbuf base, dead before k_caps writes hbuf):
// 0:G  1..8:Q_1..Q_8 (Q_i=W3^i; K_i=Q_i^T)  9..15:T_1..7  16..22:H_1..7  23:gtab(8*196)

__device__ inline void glds16(const void* g, void* l) {
  __builtin_amdgcn_global_load_lds((const __attribute__((address_space(1))) void*)g,
                                   (__attribute__((address_space(3))) void*)l, 16, 0, 0);
}

// ---------------- prep: merged decoder/output weights (one launch) ----------------
__global__ void k_prep_io(const float* __restrict__ Wd1, const float* __restrict__ Wd2,
                          const float* __restrict__ Wo,
                          f16* __restrict__ W1p, f16* __restrict__ W2p,
                          float* __restrict__ WoT) {
  int b = blockIdx.x;
  if (b < 5600) {
    const float* Wd = (b < 2800) ? Wd1 : Wd2;
    f16* W16 = (b < 2800) ? W1p : W2p;
    int idx = (b % 2800) * NT + threadIdx.x;
    if (idx < 896 * 800) {
      int n = idx / 800, k = idx - n * 800;
      W16[idx] = (f16)((n < 784 && k < 784) ? Wd[n * 784 + k] : 0.f);
    }
  } else {
    int idx = (b - 5600) * NT + threadIdx.x;
    if (idx < 784 * 16) {
      int f = idx >> 4, n = idx & 15;
      WoT[idx] = (n < 10) ? Wo[n * 784 + f] : 0.f;   // [784][16] — coalesced broadcast reads
    }
  }
}

// ---------------- prep: level-1 — G = W1^T W2 ; Q2 = W3 W3 ; Q1 = copy(W3) ----------------
__global__ void k_prep_gq(const float* __restrict__ W1, const float* __restrict__ W2,
                          const float* __restrict__ W3, float* __restrict__ scr) {
  __shared__ float red[256];
  const int tid = threadIdx.x;
  int b = blockIdx.x;
  if (b < 1202) {
    int ta = (b < 601);
    const float* A = ta ? W1 : W3;
    const float* B = ta ? W2 : W3;
    float* C = ta ? scr : (scr + (size_t)2 * SSE);
    int u = ta ? b : (b - 601);
    int o = u * 64 + (tid & 63);
    int ks = tid >> 6;
    float s = 0.f;
    int p = 0, r = 0;
    if (o < 38416) {
      p = o / 196; r = o - p * 196;
      const int c0 = ks * 49;
      #pragma unroll 7
      for (int c = c0; c < c0 + 49; ++c) {
        float a = ta ? A[c * 196 + p] : A[p * 196 + c];
        s += a * B[c * 196 + r];
      }
    }
    red[tid] = s;
    __syncthreads();
    if (tid < 64 && o < 38416)
      C[p * 196 + r] = red[tid] + red[tid + 64] + red[tid + 128] + red[tid + 192];
  } else {
    int idx = (b - 1202) * NT + tid;
    if (idx < 38416) scr[(size_t)SSE + idx] = W3[idx];
  }
}

// ---------------- prep: table-driven batched 196x196 products (stages 0..3) ----------------
// L0: Q3,Q4,T1,T2     L1: Q5..Q8,T3,T4,H1,H2     L2: T5,T6,T7,H3,H4 (+vec at y==5)   L3: H5,H6,H7
__constant__ int MMA[4][8] = {{2,2,1,2,0,0,0,0},{4,4,4,4,3,4,9,10},
                              {5,6,7,11,12,0,0,0},{13,14,15,0,0,0,0,0}};
__constant__ int MMB[4][8] = {{1,2,0,0,0,0,0,0},{1,2,3,4,0,0,1,2},
                              {0,0,0,3,4,0,0,0},{5,6,7,0,0,0,0,0}};
__constant__ int MMC[4][8] = {{3,4,9,10,0,0,0,0},{5,6,7,8,11,12,16,17},
                              {13,14,15,18,19,0,0,0},{20,21,22,0,0,0,0,0}};
__constant__ int MMT[4][8] = {{0,0,1,1,0,0,0,0},{0,0,0,0,1,1,0,0},
                              {1,1,1,0,0,0,0,0},{0,0,0,0,0,0,0,0}};

__global__ __launch_bounds__(NT, 4)
void k_mmb(float* __restrict__ scr, int stage,
           const float* __restrict__ W2, const float* __restrict__ b1,
           const float* __restrict__ b3, float* __restrict__ d8out) {
  __shared__ float red[256];
  __shared__ float z[196], cj[196], dd[196], tmp[196];
  const int tid = threadIdx.x;
  const int y = blockIdx.y;

  if (stage == 2 && y == 5) {
    // ---- vectors: one block per i (c-chain, d_i, g_i, ghat_i, d8) ----
    if (blockIdx.x >= 8) return;
    const int i = blockIdx.x;
    const float* G = scr;
    const float* Qbase = scr + (size_t)SSE;
    float* gtab = scr + (size_t)23 * SSE;
    const float* W3c = Qbase;              // Q1 slot = W3 copy
    for (int t = tid; t < 196; t += NT) {
      float s = 0.f;
      for (int f = 0; f < 196; ++f) s += b1[f] * W2[f * 196 + t];
      z[t] = s; dd[t] = 0.f; cj[t] = b3[t];
    }
    __syncthreads();
    for (int j = 0; j < i; ++j) {
      for (int t = tid; t < 196; t += NT) {
        float s = 0.f;
        for (int c = 0; c < 196; ++c) s += W3c[t * 196 + c] * cj[c];
        tmp[t] = s; dd[t] += cj[t];
      }
      __syncthreads();
      for (int t = tid; t < 196; t += NT) cj[t] = tmp[t];
      __syncthreads();
    }
    if (i == 7)
      for (int t = tid; t < 196; t += NT) d8out[t] = dd[t] + cj[t];
    for (int t = tid; t < 196; t += NT) {
      float s = z[t];
      for (int k = 0; k < 196; ++k) s += G[k * 196 + t] * dd[k];
      tmp[t] = s;
    }
    __syncthreads();
    for (int t = tid; t < 196; t += NT) {
      float s;
      if (i == 0) s = tmp[t];
      else {
        const float* Qi = Qbase + (size_t)(i - 1) * SSE;
        s = 0.f;
        for (int n = 0; n < 196; ++n) s += Qi[n * 196 + t] * tmp[n];
      }
      gtab[i * 196 + t] = s;
    }
    return;
  }

  const float* A = scr + (size_t)MMA[stage][y] * SSE;
  const float* B = scr + (size_t)MMB[stage][y] * SSE;
  float*       C = scr + (size_t)MMC[stage][y] * SSE;
  const int ta = MMT[stage][y];
  int o = blockIdx.x * 64 + (tid & 63);
  int ks = tid >> 6;
  float s = 0.f;
  int p = 0, r = 0;
  if (o < 38416) {
    p = o / 196; r = o - p * 196;
    const int c0 = ks * 49;
    #pragma unroll 7
    for (int c = c0; c < c0 + 49; ++c) {
      float a = ta ? A[c * 196 + p] : A[p * 196 + c];
      s += a * B[c * 196 + r];
    }
  }
  red[tid] = s;
  __syncthreads();
  if (tid < 64 && o < 38416)
    C[p * 196 + r] = red[tid] + red[tid + 64] + red[tid + 128] + red[tid + 192];
}

// ---------------- prep: pack Wpk[9 slots][208 n][224 k] f16 hi/lo ----------------
__global__ void k_prep_pack(const float* __restrict__ scr,
                            f16* __restrict__ Wph, f16* __restrict__ Wpl) {
  int idx = blockIdx.x * NT + threadIdx.x;
  if (idx >= 9 * 208 * 224) return;
  int s = idx / (208 * 224), rem = idx - s * (208 * 224);
  int n = rem / 224, k = rem - n * 224;
  float v = 0.f;
  if (k < 196) {
    if (n < 196) {
      if (s == 8) v = scr[(size_t)8 * SSE + n * 196 + k];       // K8 = Q8^T
      else {
        const float* M = (s == 0) ? scr : (scr + (size_t)(16 + s - 1) * SSE);
        v = M[k * 196 + n];
      }
    } else if (n == 196 && s < 8) {
      v = scr[(size_t)23 * SSE + s * 196 + k];
    }
  }
  f16 hi = (f16)v;
  Wph[idx] = hi;
  Wpl[idx] = (f16)(v - (float)hi);
}

// ---------------- capsule kernel (r5-exact: 455us verified) ----------------
__global__ __launch_bounds__(NTC, 4)
void k_caps(const float* __restrict__ x,
            const f16* __restrict__ Wph, const f16* __restrict__ Wpl,
            const float* __restrict__ d8g,
            f16* __restrict__ hbuf) {
  __shared__ __align__(16) char smem[70656];
  f16*   vAhi = (f16*)smem;                 // [64][232]
  f16*   vAlo = (f16*)(smem + 29696);       // [64][232]
  float* Sful = (float*)(smem + 59392);     // [8 i][16 elem][4 t][4 s]
  float* Rl   = (float*)(smem + 67584);     // [8 i][64 row]
  float* Cm   = (float*)(smem + 69632);     // [16 elem][4 t][4 s]

  const int tid  = threadIdx.x;
  const int w    = tid >> 6;
  const int lane = tid & 63;
  const int l15  = lane & 15;
  const int quad = lane >> 4;
  const int e0   = blockIdx.x * 16;
  const bool haveJ1 = (w + 8) < 13;

  for (int idx = tid; idx < 16 * 196; idx += NTC) {
    int elem = idx / 196, g = idx - elem * 196;
    int t = g / 49, f = (g - t * 49) * 4;
    floatx4 v4 = *(const floatx4*)&x[(size_t)(e0 + elem) * 784 + g * 4];
    half4 h4, l4;
    #pragma unroll
    for (int q = 0; q < 4; ++q) {
      f16 h = (f16)v4[q];
      h4[q] = h;
      l4[q] = (f16)(v4[q] - (float)h);
    }
    int vo = (elem * 4 + t) * 232 + f;
    *(half4*)&vAhi[vo] = h4;
    *(half4*)&vAlo[vo] = l4;
  }
  for (int p = tid; p < 64 * 36; p += NTC) {
    int row = p / 36, c = 196 + (p - (p / 36) * 36);
    vAhi[row * 232 + c] = (f16)0;
    vAlo[row * 232 + c] = (f16)0;
  }
  for (int p = tid; p < 2048; p += NTC) Sful[p] = 0.f;
  __syncthreads();

  float vv0[4][4], vv1[4][4];
  {
    int c0 = w * 16 + l15;
    int c1 = 128 + w * 16 + l15;
    #pragma unroll
    for (int mt = 0; mt < 4; ++mt)
      #pragma unroll
      for (int s = 0; s < 4; ++s) {
        int ro = ((mt * 4 + quad) * 4 + s) * 232;
        vv0[mt][s] = (float)vAhi[ro + c0] + (float)vAlo[ro + c0];
        vv1[mt][s] = haveJ1 ? ((float)vAhi[ro + c1] + (float)vAlo[ro + c1]) : 0.f;
      }
  }

  #pragma unroll 1
  for (int i = 0; i < 8; ++i) {
    floatx4 acc0[4], acc1[4];
    #pragma unroll
    for (int mt = 0; mt < 4; ++mt) {
      acc0[mt] = (floatx4){0.f, 0.f, 0.f, 0.f};
      acc1[mt] = (floatx4){0.f, 0.f, 0.f, 0.f};
    }
    const int wb0 = ((i * 208 + w * 16 + l15) * 224) + quad * 8;
    const int wb1 = ((i * 208 + (w + 8) * 16 + l15) * 224) + quad * 8;
    #pragma unroll
    for (int ks = 0; ks < 7; ++ks) {
      half8 ah[4], al[4];
      #pragma unroll
      for (int mt = 0; mt < 4; ++mt) {
        int ao = (mt * 16 + l15) * 232 + ks * 32 + quad * 8;
        ah[mt] = *(const half8*)&vAhi[ao];
        al[mt] = *(const half8*)&vAlo[ao];
      }
      {
        half8 bh = *(const half8*)&Wph[wb0 + ks * 32];
        half8 bl = *(const half8*)&Wpl[wb0 + ks * 32];
        #pragma unroll
        for (int mt = 0; mt < 4; ++mt) {
          acc0[mt] = __builtin_amdgcn_mfma_f32_16x16x32_f16(ah[mt], bh, acc0[mt], 0, 0, 0);
          acc0[mt] = __builtin_amdgcn_mfma_f32_16x16x32_f16(ah[mt], bl, acc0[mt], 0, 0, 0);
          acc0[mt] = __builtin_amdgcn_mfma_f32_16x16x32_f16(al[mt], bh, acc0[mt], 0, 0, 0);
        }
      }
      if (haveJ1) {
        half8 bh = *(const half8*)&Wph[wb1 + ks * 32];
        half8 bl = *(const half8*)&Wpl[wb1 + ks * 32];
        #pragma unroll
        for (int mt = 0; mt < 4; ++mt) {
          acc1[mt] = __builtin_amdgcn_mfma_f32_16x16x32_f16(ah[mt], bh, acc1[mt], 0, 0, 0);
          acc1[mt] = __builtin_amdgcn_mfma_f32_16x16x32_f16(ah[mt], bl, acc1[mt], 0, 0, 0);
          acc1[mt] = __builtin_amdgcn_mfma_f32_16x16x32_f16(al[mt], bh, acc1[mt], 0, 0, 0);
        }
      }
    }
    #pragma unroll
    for (int mt = 0; mt < 4; ++mt) {
      float part[16];
      #pragma unroll
      for (int t = 0; t < 4; ++t)
        #pragma unroll
        for (int s = 0; s < 4; ++s)
          part[t * 4 + s] = acc0[mt][t] * vv0[mt][s] + acc1[mt][t] * vv1[mt][s];
      #pragma unroll
      for (int p = 0; p < 16; ++p) {
        ROWSHR_ADD(part[p], 8);
        ROWSHR_ADD(part[p], 4);
        ROWSHR_ADD(part[p], 2);
        ROWSHR_ADD(part[p], 1);
      }
      if (l15 == 0) {
        int elem = mt * 4 + quad;
        #pragma unroll
        for (int t = 0; t < 4; ++t)
          #pragma unroll
          for (int s = 0; s < 4; ++s)
            atomicAdd(&Sful[((i * 16 + elem) * 4 + t) * 4 + s], part[t * 4 + s]);
      }
    }
    if (w == 4 && l15 == 4) {
      #pragma unroll
      for (int mt = 0; mt < 4; ++mt)
        *(floatx4*)&Rl[i * 64 + mt * 16 + quad * 4] = acc1[mt];
    }
  }
  __syncthreads();

  if (tid < 16) {
    const int e = tid;
    float C[4][4] = {{1,0,0,0},{0,1,0,0},{0,0,1,0},{0,0,0,1}};
    #pragma unroll 1
    for (int i = 0; i < 8; ++i) {
      float M[4][4];
      #pragma unroll
      for (int a = 0; a < 4; ++a) {
        floatx4 mm = *(const floatx4*)&Sful[((i * 16 + e) * 4 + a) * 4];
        #pragma unroll
        for (int b = 0; b < 4; ++b) M[a][b] = mm[b];
      }
      floatx4 rv = *(const floatx4*)&Rl[i * 64 + e * 4];
      float T1[4][4], Cr[4];
      #pragma unroll
      for (int t = 0; t < 4; ++t)
        #pragma unroll
        for (int b = 0; b < 4; ++b)
          T1[t][b] = C[t][0]*M[0][b] + C[t][1]*M[1][b] + C[t][2]*M[2][b] + C[t][3]*M[3][b];
      #pragma unroll
      for (int s = 0; s < 4; ++s)
        Cr[s] = C[s][0]*rv[0] + C[s][1]*rv[1] + C[s][2]*rv[2] + C[s][3]*rv[3];
      float P[4][4];
      #pragma unroll
      for (int t = 0; t < 4; ++t) {
        float S[4];
        #pragma unroll
        for (int s = 0; s < 4; ++s)
          S[s] = T1[t][0]*C[s][0] + T1[t][1]*C[s][1] + T1[t][2]*C[s][2] + T1[t][3]*C[s][3] + Cr[s];
        float m = fmaxf(fmaxf(S[0], S[1]), fmaxf(S[2], S[3]));
        float e0_ = __expf(S[0] - m), e1 = __expf(S[1] - m);
        float e2 = __expf(S[2] - m), e3 = __expf(S[3] - m);
        float inv = 1.f / (e0_ + e1 + e2 + e3);
        P[t][0] = e0_ * inv; P[t][1] = e1 * inv; P[t][2] = e2 * inv; P[t][3] = e3 * inv;
      }
      float Cn[4][4];
      #pragma unroll
      for (int t = 0; t < 4; ++t)
        #pragma unroll
        for (int s = 0; s < 4; ++s)
          Cn[t][s] = P[t][0]*C[0][s] + P[t][1]*C[1][s] + P[t][2]*C[2][s] + P[t][3]*C[3][s];
      #pragma unroll
      for (int t = 0; t < 4; ++t)
        #pragma unroll
        for (int s = 0; s < 4; ++s) C[t][s] = Cn[t][s];
    }
    #pragma unroll
    for (int t = 0; t < 4; ++t)
      *(floatx4*)&Cm[e * 16 + t * 4] = (floatx4){C[t][0], C[t][1], C[t][2], C[t][3]};
  }
  __syncthreads();

  {
    floatx4 acu0[4], acu1[4];
    #pragma unroll
    for (int mt = 0; mt < 4; ++mt) {
      acu0[mt] = (floatx4){0.f, 0.f, 0.f, 0.f};
      acu1[mt] = (floatx4){0.f, 0.f, 0.f, 0.f};
    }
    const int wb0 = ((8 * 208 + w * 16 + l15) * 224) + quad * 8;
    const int wb1 = ((8 * 208 + (w + 8) * 16 + l15) * 224) + quad * 8;
    #pragma unroll
    for (int ks = 0; ks < 7; ++ks) {
      half8 ah[4], al[4];
      #pragma unroll
      for (int mt = 0; mt < 4; ++mt) {
        int ao = (mt * 16 + l15) * 232 + ks * 32 + quad * 8;
        ah[mt] = *(const half8*)&vAhi[ao];
        al[mt] = *(const half8*)&vAlo[ao];
      }
      {
        half8 bh = *(const half8*)&Wph[wb0 + ks * 32];
        half8 bl = *(const half8*)&Wpl[wb0 + ks * 32];
        #pragma unroll
        for (int mt = 0; mt < 4; ++mt) {
          acu0[mt] = __builtin_amdgcn_mfma_f32_16x16x32_f16(ah[mt], bh, acu0[mt], 0, 0, 0);
          acu0[mt] = __builtin_amdgcn_mfma_f32_16x16x32_f16(ah[mt], bl, acu0[mt], 0, 0, 0);
          acu0[mt] = __builtin_amdgcn_mfma_f32_16x16x32_f16(al[mt], bh, acu0[mt], 0, 0, 0);
        }
      }
      if (haveJ1) {
        half8 bh = *(const half8*)&Wph[wb1 + ks * 32];
        half8 bl = *(const half8*)&Wpl[wb1 + ks * 32];
        #pragma unroll
        for (int mt = 0; mt < 4; ++mt) {
          acu1[mt] = __builtin_amdgcn_mfma_f32_16x16x32_f16(ah[mt], bh, acu1[mt], 0, 0, 0);
          acu1[mt] = __builtin_amdgcn_mfma_f32_16x16x32_f16(ah[mt], bl, acu1[mt], 0, 0, 0);
          acu1[mt] = __builtin_amdgcn_mfma_f32_16x16x32_f16(al[mt], bh, acu1[mt], 0, 0, 0);
        }
      }
    }
    const int f0 = w * 16 + l15;
    const int f1 = 128 + w * 16 + l15;
    const bool doF1 = haveJ1 && (f1 < 196);
    float d80 = d8g[f0];
    float d81 = doF1 ? d8g[f1] : 0.f;
    #pragma unroll
    for (int mt = 0; mt < 4; ++mt) {
      int elem = mt * 4 + quad;
      floatx4 c0 = *(const floatx4*)&Cm[elem * 16 + 0];
      floatx4 c1 = *(const floatx4*)&Cm[elem * 16 + 4];
      floatx4 c2 = *(const floatx4*)&Cm[elem * 16 + 8];
      floatx4 c3 = *(const floatx4*)&Cm[elem * 16 + 12];
      {
        floatx4 u = acu0[mt];
        float h0 = c0[0]*u[0] + c0[1]*u[1] + c0[2]*u[2] + c0[3]*u[3] + d80;
        float h1 = c1[0]*u[0] + c1[1]*u[1] + c1[2]*u[2] + c1[3]*u[3] + d80;
        float h2 = c2[0]*u[0] + c2[1]*u[1] + c2[2]*u[2] + c2[3]*u[3] + d80;
        float h3 = c3[0]*u[0] + c3[1]*u[1] + c3[2]*u[2] + c3[3]*u[3] + d80;
        size_t base = (size_t)(e0 + elem) * 800;
        hbuf[base + 0 * 196 + f0] = (f16)h0;
        hbuf[base + 1 * 196 + f0] = (f16)h1;
        hbuf[base + 2 * 196 + f0] = (f16)h2;
        hbuf[base + 3 * 196 + f0] = (f16)h3;
      }
      if (doF1) {
        floatx4 u = acu1[mt];
        float h0 = c0[0]*u[0] + c0[1]*u[1] + c0[2]*u[2] + c0[3]*u[3] + d81;
        float h1 = c1[0]*u[0] + c1[1]*u[1] + c1[2]*u[2] + c1[3]*u[3] + d81;
        float h2 = c2[0]*u[0] + c2[1]*u[1] + c2[2]*u[2] + c2[3]*u[3] + d81;
        float h3 = c3[0]*u[0] + c3[1]*u[1] + c3[2]*u[2] + c3[3]*u[3] + d81;
        size_t base = (size_t)(e0 + elem) * 800;
        hbuf[base + 0 * 196 + f1] = (f16)h0;
        hbuf[base + 1 * 196 + f1] = (f16)h1;
        hbuf[base + 2 * 196 + f1] = (f16)h2;
        hbuf[base + 3 * 196 + f1] = (f16)h3;
      }
    }
  }
  for (int idx = tid; idx < 256; idx += NTC)
    hbuf[(size_t)(e0 + (idx >> 4)) * 800 + 784 + (idx & 15)] = (f16)0;
}

// ---------------- decoder layer GEMM (r5-exact, 2 blocks/CU verified) ----------------
__global__ __launch_bounds__(NT, 2)
void k_dec(const f16* __restrict__ A, const f16* __restrict__ Bw,
           const float* __restrict__ bias, f16* __restrict__ C, int do_relu) {
  __shared__ __align__(16) f16 As[128 * 32];
  __shared__ __align__(16) f16 Bs[128 * 32];
  const int tid = threadIdx.x, w = tid >> 6, lane = tid & 63;
  const int l15 = lane & 15, quad = lane >> 4;
  const int m0 = blockIdx.x * 128, n0 = blockIdx.y * 128;
  const int wm = w & 1, wn = w >> 1;
  const int srow = lane >> 2, soff = (lane & 3) * 8;

  floatx4 acc[4][4];
  #pragma unroll
  for (int nt = 0; nt < 4; ++nt) {
    int col = n0 + wn * 64 + nt * 16 + l15;
    float bb = (col < 784) ? bias[col] : 0.f;
    #pragma unroll
    for (int mt = 0; mt < 4; ++mt) acc[mt][nt] = (floatx4){bb, bb, bb, bb};
  }

  for (int kk = 0; kk < 25; ++kk) {
    __syncthreads();
    #pragma unroll
    for (int i = 0; i < 2; ++i) {
      int r = w * 32 + i * 16;
      glds16(&A[(size_t)(m0 + r + srow) * 800 + kk * 32 + soff], &As[r * 32]);
      glds16(&Bw[(size_t)(n0 + r + srow) * 800 + kk * 32 + soff], &Bs[r * 32]);
    }
    __syncthreads();
    half8 af[4], bf[4];
    #pragma unroll
    for (int mt = 0; mt < 4; ++mt)
      af[mt] = *(const half8*)&As[(wm * 64 + mt * 16 + l15) * 32 + quad * 8];
    #pragma unroll
    for (int nt = 0; nt < 4; ++nt)
      bf[nt] = *(const half8*)&Bs[(wn * 64 + nt * 16 + l15) * 32 + quad * 8];
    #pragma unroll
    for (int mt = 0; mt < 4; ++mt)
      #pragma unroll
      for (int nt = 0; nt < 4; ++nt)
        acc[mt][nt] = __builtin_amdgcn_mfma_f32_16x16x32_f16(af[mt], bf[nt], acc[mt][nt], 0, 0, 0);
  }

  #pragma unroll
  for (int nt = 0; nt < 4; ++nt) {
    int gcol = n0 + wn * 64 + nt * 16 + l15;
    if (gcol < 800) {
      #pragma unroll
      for (int mt = 0; mt < 4; ++mt) {
        #pragma unroll
        for (int r = 0; r < 4; ++r) {
          int grow = m0 + wm * 64 + mt * 16 + quad * 4 + r;
          float v = acc[mt][nt][r];
          if (do_relu) v = fmaxf(v, 0.f);
          C[(size_t)grow * 800 + gcol] = (f16)v;
        }
      }
    }
  }
}

// ---------------- logits + softmax (r5-exact, WoT [784][16] coalesced) ----------------
__global__ __launch_bounds__(NT, 4)
void k_logits(const f16* __restrict__ d2, const float* __restrict__ WoT,
              const float* __restrict__ bo, float* __restrict__ out) {
  __shared__ __align__(16) f16 ds[16 * 800];
  __shared__ float lg[160];
  const int tid = threadIdx.x;
  const size_t e0 = (size_t)blockIdx.x * 16;
  for (int i = tid; i < 16 * 98; i += NT) {
    int e = i / 98, c = (i - e * 98) * 8;
    *(half8*)&ds[e * 800 + c] = *(const half8*)&d2[(e0 + e) * 800 + c];
  }
  __syncthreads();
  {
    int e = tid >> 4, n = tid & 15;
    const f16* dp = &ds[e * 800];
    float s = 0.f;
    #pragma unroll 4
    for (int f = 0; f < 784; ++f) s += (float)dp[f] * WoT[f * 16 + n];
    if (n < 10) lg[e * 10 + n] = s + bo[n];
  }
  __syncthreads();
  if (tid < 16) {
    float l[10], m = -1e30f;
    #pragma unroll
    for (int n = 0; n < 10; ++n) { l[n] = lg[tid * 10 + n]; m = fmaxf(m, l[n]); }
    float sum = 0.f;
    #pragma unroll
    for (int n = 0; n < 10; ++n) { l[n] = __expf(l[n] - m); sum += l[n]; }
    float inv = 1.f / sum;
    #pragma unroll
    for (int n = 0; n < 10; ++n) out[(e0 + tid) * 10 + n] = l[n] * inv;
  }
}

extern "C" void kernel_launch(void* const* d_in, const int* in_sizes, int n_in,
                              void* d_out, int out_size, void* d_ws, size_t ws_size,
                              hipStream_t stream) {
  const float* x   = (const float*)d_in[0];
  const float* W1  = (const float*)d_in[1];
  const float* b1  = (const float*)d_in[2];
  const float* W2  = (const float*)d_in[3];
  // b2 (d_in[4]) cancels in the softmax (row-constant) — unused.
  const float* W3  = (const float*)d_in[5];
  const float* b3  = (const float*)d_in[6];
  const float* Wd1 = (const float*)d_in[7];
  const float* bd1 = (const float*)d_in[8];
  const float* Wd2 = (const float*)d_in[9];
  const float* bd2 = (const float*)d_in[10];
  const float* Wo  = (const float*)d_in[11];
  const float* bo  = (const float*)d_in[12];
  float* out = (float*)d_out;

  char* ws = (char*)d_ws;
  f16*   Wd1p  = (f16*)(ws + WD1_OFF);
  f16*   Wd2p  = (f16*)(ws + WD2_OFF);
  float* WoTws = (float*)(ws + WOT_OFF);
  float* d8ws  = (float*)(ws + D8_OFF);
  f16*   hbuf  = (f16*)(ws + HBUF_OFF);
  f16*   d1buf = (f16*)(ws + D1_OFF);
  f16*   Wph   = (f16*)(ws + WPKH_OFF);
  f16*   Wpl   = (f16*)(ws + WPKL_OFF);
  float* scr   = (float*)(ws + HBUF_OFF);   // fp32 prep scratch, dead before k_caps writes hbuf

  // merged IO prep (wd1, wd2, wo) — one launch
  k_prep_io<<<5649, NT, 0, stream>>>(Wd1, Wd2, Wo, Wd1p, Wd2p, WoTws);
  // level-1: G, Q2, Q1-copy — one launch
  k_prep_gq<<<1353, NT, 0, stream>>>(W1, W2, W3, scr);
  // levels 2..5: table-driven batched products (+vec folded into stage 2)
  k_mmb<<<dim3(601, 4), NT, 0, stream>>>(scr, 0, W2, b1, b3, d8ws);
  k_mmb<<<dim3(601, 8), NT, 0, stream>>>(scr, 1, W2, b1, b3, d8ws);
  k_mmb<<<dim3(601, 6), NT, 0, stream>>>(scr, 2, W2, b1, b3, d8ws);
  k_mmb<<<dim3(601, 3), NT, 0, stream>>>(scr, 3, W2, b1, b3, d8ws);
  // pack f16 hi/lo weight block
  k_prep_pack<<<(9 * 208 * 224 + NT - 1) / NT, NT, 0, stream>>>(scr, Wph, Wpl);

  k_caps<<<32768 / 16, NTC, 0, stream>>>(x, Wph, Wpl, d8ws, hbuf);
  k_dec<<<dim3(32768 / 128, 7), NT, 0, stream>>>(hbuf, Wd1p, bd1, d1buf, 1);
  k_dec<<<dim3(32768 / 128, 7), NT, 0, stream>>>(d1buf, Wd2p, bd2, hbuf, 0);
  k_logits<<<32768 / 16, NT, 0, stream>>>(hbuf, WoTws, bo, out);
}